// Round 1
// 336.434 us; speedup vs baseline: 1.0070x; 1.0070x over previous
//
#include <hip/hip_runtime.h>

// SkelConv via bf16 MFMA implicit-GEMM, v2: pipelined staging.
// Joints grouped into 14 M=16 tiles; K = 16 ci x 16 taps = 256 (8 x
// mfma_f32_16x16x32_bf16). x staged TRANSPOSED in LDS (bf16, 48 B col
// stride, 16B-aligned b128 B-reads, 2-way-free banking).
// v2 changes vs v1 (341.8 us session best):
//  - staging vectorized: float4 loads (8 x 128B coalesced segments/instr),
//    item map (ci-pair = i&7, col-quad = i>>3); halo rebased to -8 so all
//    dwordx4 are 16B-aligned and edge quads are whole-in/whole-out.
//  - double-buffered 128-col subtiles, register prefetch (async-STAGE
//    split): issue loads -> MFMA phase -> convert+ds_write -> barrier.
//    LDS 25.3KB -> 13.8KB (occupancy headroom).
//  - XCD-chunked block swizzle: 14 tiles sharing one (b,tt) x-slice pin to
//    one XCD's L2.

typedef __attribute__((ext_vector_type(8))) short s16x8;
typedef __attribute__((ext_vector_type(4))) float f32x4;

#define T_LEN 8192
#define B_N 32
#define C_INCH 103
#define C_OUTCH 206
#define NTILE 14
#define TTILE 512
#define NSUB 4
#define SUBT 128             // TTILE / NSUB
#define SUBC 144             // SUBT + 16 halo; LDS col c <-> gt = t0s - 8 + c
#define LDS_STRIDE 48        // bytes per staged column (16 ci * 2B, padded)
#define KSTEPS 8             // K = 256
#define NBLOCKS (NTILE * B_N * (T_LEN / TTILE))   // 7168
#define CPX (NBLOCKS / 8)                          // 896 blocks per XCD chunk
#define NITEMS (8 * (SUBC / 4))                    // 288 staging items

// bf16 round-to-nearest-even, returns raw bits
__device__ __forceinline__ unsigned short f2bf(float f) {
  union { float f; unsigned u; } v; v.f = f;
  unsigned r = v.u + 0x7FFFu + ((v.u >> 16) & 1u);
  return (unsigned short)(r >> 16);
}

__device__ __forceinline__ void tile_params(int t, int& co_b, int& nr, int& ci_b) {
  if (t == 0)       { co_b = 0;   nr = 14; ci_b = 0;  }      // jt0
  else if (t == 1)  { co_b = 14;  nr = 8;  ci_b = 0;  }      // jt1
  else if (t <= 12) { int j = t - 1;                          // pair (2j, 2j+1)
                      co_b = 14 + (2*j - 1) * 8; nr = 16; ci_b = 8*j - 1; }
  else              { co_b = 198; nr = 8;  ci_b = 87; }      // jt24
}

// Pack masked weights in exact MFMA A-fragment layout, bf16 (unchanged v1).
__global__ void prep_weights(const float* __restrict__ w,
                             const float* __restrict__ mask,
                             unsigned short* __restrict__ wA) {
  int tile = blockIdx.x >> 3;
  int s    = blockIdx.x & 7;
  int l    = threadIdx.x;            // 0..63
  int co_b, nr, ci_b; tile_params(tile, co_b, nr, ci_b);
  int m  = l & 15;
  int q  = l >> 4;
  int kk = 2 * s + (q >> 1);
  int ci0 = (q & 1) * 8;
  unsigned short* dst = wA + ((size_t)((tile * 8 + s) * 64 + l)) * 8;
  for (int j = 0; j < 8; ++j) {
    int ci = ci_b + ci0 + j;
    float v = 0.f;
    if (m < nr && kk < 15) {
      int gi = ((co_b + m) * C_INCH + ci) * 15 + kk;
      v = w[gi] * mask[gi];
    }
    dst[j] = f2bf(v);
  }
}

// Staging item i: ci-pair p = i&7 (rows ci_b+2p, ci_b+2p+1), col-quad
// c4 = i>>3 (LDS cols 4c4..4c4+3, gt0 = t0s-8+4c4). Loads are 16B-aligned
// dwordx4; per wave the 8 p-lanes x 8 quad-groups form 8 contiguous 128B
// row segments. Edge quads never straddle t=0/T_LEN (gt0 % 4 == 0).
__device__ __forceinline__ void stage_load(const float* __restrict__ x,
                                           int rowbase, int t0s, int i,
                                           f32x4& va, f32x4& vb) {
  int p  = i & 7;
  int c4 = i >> 3;
  int gt0 = t0s - 8 + 4 * c4;
  f32x4 z = {0.f, 0.f, 0.f, 0.f};
  va = z; vb = z;
  if ((unsigned)gt0 <= (unsigned)(T_LEN - 4)) {
    const float* pa = x + (size_t)(rowbase + 2 * p) * T_LEN + gt0;
    va = *(const f32x4*)pa;
    vb = *(const f32x4*)(pa + T_LEN);
  }
}

__device__ __forceinline__ void stage_write(unsigned short* __restrict__ buf,
                                            int i, f32x4 va, f32x4 vb) {
  int p  = i & 7;
  int c4 = i >> 3;
  char* base = (char*)buf + (4 * c4) * LDS_STRIDE + 4 * p;
#pragma unroll
  for (int j = 0; j < 4; ++j) {
    unsigned pk = (unsigned)f2bf(va[j]) | ((unsigned)f2bf(vb[j]) << 16);
    *(unsigned*)(base + j * LDS_STRIDE) = pk;   // 4-way bank alias: ~free
  }
}

__global__ __launch_bounds__(256, 4) void skelconv_mfma(
    const float* __restrict__ x, const unsigned short* __restrict__ wA,
    const float* __restrict__ biases, float* __restrict__ out) {
  int bid = blockIdx.x;
  // XCD-chunked swizzle (bijective, 7168 % 8 == 0): hardware round-robins
  // consecutive bids over 8 XCDs; this gives XCD k the contiguous logical
  // range [k*896, (k+1)*896) so the 14 tiles of each (b,tt) group share L2.
  int lid  = (bid & 7) * CPX + (bid >> 3);
  int tile = lid % NTILE;            // tile fastest -> x-slice reuse
  int rem  = lid / NTILE;
  int tt   = rem & 15;               // 8192/512 t-tiles
  int b    = rem >> 4;
  int t0   = tt * TTILE;
  int co_b, nr, ci_b; tile_params(tile, co_b, nr, ci_b);
  int rowbase = b * C_INCH + ci_b;

  __shared__ unsigned short xs[2][SUBC * LDS_STRIDE / 2];   // 2 x 6912 B

  int tid  = threadIdx.x;
  int lane = tid & 63;
  int wq   = tid >> 6;               // wave's 32-col slice of each subtile
  int q    = lane >> 4;
  int n    = lane & 15;
  int e    = q & 1;                  // ci octet
  int h    = q >> 1;                 // kk low bit

  // A fragments: one dwordx4 per lane per K-step, loaded once (L2-resident).
  s16x8 afr[KSTEPS];
  const s16x8* ap = ((const s16x8*)wA) + (size_t)tile * (KSTEPS * 64);
#pragma unroll
  for (int s = 0; s < KSTEPS; ++s) afr[s] = ap[s * 64 + lane];

  float bvals[4];
#pragma unroll
  for (int r = 0; r < 4; ++r) {
    int row = q * 4 + r;
    bvals[r] = (row < nr) ? biases[co_b + row] : 0.f;
  }

  // Prologue: stage subtile 0 synchronously into xs[0].
  {
    f32x4 a0, b0, a1, b1;
    stage_load(x, rowbase, t0, tid, a0, b0);
    bool s1 = tid < (NITEMS - 256);          // 32 threads carry a 2nd item
    if (s1) stage_load(x, rowbase, t0, tid + 256, a1, b1);
    stage_write(xs[0], tid, a0, b0);
    if (s1) stage_write(xs[0], tid + 256, a1, b1);
  }
  __syncthreads();

#pragma unroll
  for (int st = 0; st < NSUB; ++st) {
    const int cur = st & 1;
    // --- issue next-subtile global loads (in flight across the MFMA phase)
    f32x4 a0, b0, a1, b1;
    const bool pf = (st + 1 < NSUB);
    const bool s1 = tid < (NITEMS - 256);
    if (pf) {
      int t0n = t0 + (st + 1) * SUBT;
      stage_load(x, rowbase, t0n, tid, a0, b0);
      if (s1) stage_load(x, rowbase, t0n, tid + 256, a1, b1);
    }
    // --- compute subtile st from xs[cur]: per wave 2 tau-tiles of 16 cols
    const char* xbase = (const char*)xs[cur];
#pragma unroll
    for (int tl = 0; tl < 2; ++tl) {
      // staged col cs = wq*32 + tl*16 + n + 2s + h + 1  (gt = t0s-8+cs)
      const char* bb = xbase + (wq * 32 + tl * 16 + n + h + 1) * LDS_STRIDE
                       + e * 16;
      f32x4 acc = {0.f, 0.f, 0.f, 0.f};
#pragma unroll
      for (int s = 0; s < KSTEPS; ++s) {
        s16x8 bfr = *(const s16x8*)(bb + s * (2 * LDS_STRIDE));
        acc = __builtin_amdgcn_mfma_f32_16x16x32_bf16(afr[s], bfr, acc, 0, 0, 0);
      }
      int tcol = t0 + st * SUBT + wq * 32 + tl * 16 + n;
#pragma unroll
      for (int r = 0; r < 4; ++r) {
        int row = q * 4 + r;           // C layout: col = lane&15, row = q*4+r
        if (row < nr)
          out[((size_t)b * C_OUTCH + co_b + row) * T_LEN + tcol] = acc[r] + bvals[r];
      }
    }
    // --- drain loads, convert + write into the other buffer, one barrier
    if (pf) {
      stage_write(xs[cur ^ 1], tid, a0, b0);
      if (s1) stage_write(xs[cur ^ 1], tid + 256, a1, b1);
    }
    __syncthreads();
  }
}

extern "C" void kernel_launch(void* const* d_in, const int* in_sizes, int n_in,
                              void* d_out, int out_size, void* d_ws, size_t ws_size,
                              hipStream_t stream) {
  const float* x      = (const float*)d_in[0];
  const float* w      = (const float*)d_in[1];
  const float* biases = (const float*)d_in[2];
  const float* mask   = (const float*)d_in[3];
  float* out = (float*)d_out;
  unsigned short* wA = (unsigned short*)d_ws;   // 14*8*64*8*2 = 114688 B

  hipLaunchKernelGGL(prep_weights, dim3(NTILE * KSTEPS), dim3(64), 0, stream,
                     w, mask, wA);
  hipLaunchKernelGGL(skelconv_mfma, dim3(NBLOCKS), dim3(256), 0, stream,
                     x, wA, biases, out);
}